// Round 1
// 1462.906 us; speedup vs baseline: 2.9400x; 2.9400x over previous
//
#include <hip/hip_runtime.h>

// ---------------------------------------------------------------------------
// Split-bf16 MFMA pipeline.
// Every fp32 operand x is split as x = xh + xl (xh = truncated-to-bf16 top
// half, xl = bf16 of the exact remainder). C += Ah*Bh + Ah*Bl + Al*Bh gives
// ~2^-14 relative product error (far below fp32-pipeline tolerance) while
// running on the 2.5 PF bf16 matrix cores instead of the 157 TF vector ALU.
//
// GEMM: 128x128 tile, BK=32, 256 threads (4 waves, 2x2 of 64x64),
// v_mfma_f32_16x16x32_bf16. LDS rows are 80 B (40 shorts): 20*row mod 32
// walks 8 distinct 16B bank slots per 16-lane quarter -> conflict-free-ish
// ds_read_b128 fragment reads and staging writes without XOR swizzles.
// ---------------------------------------------------------------------------

typedef __attribute__((ext_vector_type(8))) __bf16 bf16x8;
typedef __attribute__((ext_vector_type(4))) float f32x4;
typedef __attribute__((ext_vector_type(4))) unsigned short ushort4_t;

__device__ __forceinline__ void split_bf16(float f, unsigned short& hi, unsigned short& lo) {
  const unsigned int b = __float_as_uint(f);
  const float r = f - __uint_as_float(b & 0xFFFF0000u);   // exact remainder
  hi = (unsigned short)(b >> 16);
  lo = (unsigned short)(__float_as_uint(r) >> 16);
}

// BT=1: B is [N][K] row-major (S = Q*K^T case) -> natural k-contiguous staging.
// BT=0: B is [K][N] row-major (projection W, PV's V) -> transpose staging.
template<int BT>
__global__ __launch_bounds__(256)
void mgemm(const float* __restrict__ A, const float* __restrict__ B,
           float* __restrict__ C, int lda, int ldb, int ldc,
           long long bA, long long bB, long long bC,
           int K, int kmax_mode, int causal_skip, float scale) {
  if (causal_skip && (int)blockIdx.x > (int)blockIdx.y) return;
  A += bA * (long long)blockIdx.z;
  B += bB * (long long)blockIdx.z;
  C += bC * (long long)blockIdx.z;

  // 4 arrays x 128 rows x 40 shorts (80 B rows) = 40 KiB
  __shared__ unsigned short sm[4 * 128 * 40];
  unsigned short* __restrict__ Ah = sm;
  unsigned short* __restrict__ Al = sm + 5120;
  unsigned short* __restrict__ Bh = sm + 10240;
  unsigned short* __restrict__ Bl = sm + 15360;

  const int tid  = threadIdx.x;
  const int lane = tid & 63;
  const int wave = tid >> 6;
  const int wr = (wave >> 1) << 6;           // wave row quadrant (0/64)
  const int wc = (wave & 1) << 6;            // wave col quadrant (0/64)
  const int r0 = (int)blockIdx.y << 7;
  const int c0 = (int)blockIdx.x << 7;
  const int l15 = lane & 15, l4 = lane >> 4;

  const int sr = tid >> 3;                   // staging row 0..31 (+32*p)
  const int sk = (tid & 7) << 2;             // staging k offset 0,4,...,28

  f32x4 acc[4][4] = {};

  const int kend = kmax_mode ? (((int)blockIdx.y + 1) << 7) : K;   // PV causal clip

  for (int k0 = 0; k0 < kend; k0 += 32) {
    // ---- stage A tile (128 rows x 32 k), k-contiguous ----
#pragma unroll
    for (int p = 0; p < 4; ++p) {
      const int row = (p << 5) + sr;
      const float4 a = *(const float4*)(A + (size_t)(r0 + row) * lda + (k0 + sk));
      unsigned short h0, h1, h2, h3, l0, l1, l2, l3;
      split_bf16(a.x, h0, l0); split_bf16(a.y, h1, l1);
      split_bf16(a.z, h2, l2); split_bf16(a.w, h3, l3);
      *(ushort4_t*)(Ah + row * 40 + sk) = (ushort4_t){h0, h1, h2, h3};
      *(ushort4_t*)(Al + row * 40 + sk) = (ushort4_t){l0, l1, l2, l3};
    }
    // ---- stage B tile ----
    if (BT) {
      // B[N][K]: identical pattern, rows are output columns
#pragma unroll
      for (int p = 0; p < 4; ++p) {
        const int row = (p << 5) + sr;
        const float4 b = *(const float4*)(B + (size_t)(c0 + row) * ldb + (k0 + sk));
        unsigned short h0, h1, h2, h3, l0, l1, l2, l3;
        split_bf16(b.x, h0, l0); split_bf16(b.y, h1, l1);
        split_bf16(b.z, h2, l2); split_bf16(b.w, h3, l3);
        *(ushort4_t*)(Bh + row * 40 + sk) = (ushort4_t){h0, h1, h2, h3};
        *(ushort4_t*)(Bl + row * 40 + sk) = (ushort4_t){l0, l1, l2, l3};
      }
    } else {
      // B[K][N]: coalesced float2 rows, scattered u16 LDS writes (transpose)
#pragma unroll
      for (int p = 0; p < 8; ++p) {
        const int e = (p << 8) + tid;
        const int k = e >> 6;                 // 0..31
        const int n = (e & 63) << 1;          // 0..126 (even)
        const float2 b = *(const float2*)(B + (size_t)(k0 + k) * ldb + (c0 + n));
        unsigned short h0, l0, h1, l1;
        split_bf16(b.x, h0, l0); split_bf16(b.y, h1, l1);
        Bh[n * 40 + k] = h0; Bh[(n + 1) * 40 + k] = h1;
        Bl[n * 40 + k] = l0; Bl[(n + 1) * 40 + k] = l1;
      }
    }
    __syncthreads();

    // ---- MFMA: 16 frag reads (ds_read_b128), 48 MFMAs per wave ----
    bf16x8 bh[4], bl[4];
#pragma unroll
    for (int j = 0; j < 4; ++j) {
      const int n = wc + (j << 4) + l15;
      bh[j] = *(const bf16x8*)(Bh + n * 40 + (l4 << 3));
      bl[j] = *(const bf16x8*)(Bl + n * 40 + (l4 << 3));
    }
#pragma unroll
    for (int i = 0; i < 4; ++i) {
      const int m = wr + (i << 4) + l15;
      const bf16x8 ah = *(const bf16x8*)(Ah + m * 40 + (l4 << 3));
      const bf16x8 al = *(const bf16x8*)(Al + m * 40 + (l4 << 3));
#pragma unroll
      for (int j = 0; j < 4; ++j) {
        acc[i][j] = __builtin_amdgcn_mfma_f32_16x16x32_bf16(ah, bh[j], acc[i][j], 0, 0, 0);
        acc[i][j] = __builtin_amdgcn_mfma_f32_16x16x32_bf16(ah, bl[j], acc[i][j], 0, 0, 0);
        acc[i][j] = __builtin_amdgcn_mfma_f32_16x16x32_bf16(al, bh[j], acc[i][j], 0, 0, 0);
      }
    }
    __syncthreads();
  }

  // ---- store: C/D layout col = lane&15, row = (lane>>4)*4 + r ----
#pragma unroll
  for (int i = 0; i < 4; ++i) {
    const int rb = r0 + wr + (i << 4) + (l4 << 2);
#pragma unroll
    for (int j = 0; j < 4; ++j) {
      const int cc = c0 + wc + (j << 4) + l15;
#pragma unroll
      for (int r = 0; r < 4; ++r)
        C[(size_t)(rb + r) * ldc + cc] = acc[i][j][r] * scale;
    }
  }
}

// fp32 causal softmax in place, one block per row. P[j>i] = 0. (unchanged)
__global__ __launch_bounds__(256) void softmax_f32(float* __restrict__ S) {
  const int i = blockIdx.x;
  float* row = S + ((size_t)blockIdx.y * 2048 + (size_t)i) * 2048;
  const int tid = threadIdx.x;
  const int lane = tid & 63;
  const int wave = tid >> 6;
  const int j0 = tid * 8;

  float4 x0 = *(const float4*)(row + j0);
  float4 x1 = *(const float4*)(row + j0 + 4);
  float v[8] = {x0.x, x0.y, x0.z, x0.w, x1.x, x1.y, x1.z, x1.w};

  float m = -3.4e38f;
#pragma unroll
  for (int e = 0; e < 8; ++e)
    if (j0 + e <= i) m = fmaxf(m, v[e]);
  __shared__ float red[4];
#pragma unroll
  for (int off = 32; off; off >>= 1) m = fmaxf(m, __shfl_xor(m, off));
  if (lane == 0) red[wave] = m;
  __syncthreads();
  const float M = fmaxf(fmaxf(red[0], red[1]), fmaxf(red[2], red[3]));

  float p[8];
  float s = 0.f;
#pragma unroll
  for (int e = 0; e < 8; ++e) {
    p[e] = (j0 + e <= i) ? __expf(v[e] - M) : 0.f;
    s += p[e];
  }
#pragma unroll
  for (int off = 32; off; off >>= 1) s += __shfl_xor(s, off);
  __syncthreads();
  if (lane == 0) red[wave] = s;
  __syncthreads();
  const float inv = 1.0f / (red[0] + red[1] + red[2] + red[3]);

  float4 o0 = {p[0] * inv, p[1] * inv, p[2] * inv, p[3] * inv};
  float4 o1 = {p[4] * inv, p[5] * inv, p[6] * inv, p[7] * inv};
  *(float4*)(row + j0) = o0;
  *(float4*)(row + j0 + 4) = o1;
}

extern "C" void kernel_launch(void* const* d_in, const int* in_sizes, int n_in,
                              void* d_out, int out_size, void* d_ws, size_t ws_size,
                              hipStream_t stream) {
  const float* X  = (const float*)d_in[0];
  const float* Wq = (const float*)d_in[1];
  const float* Wk = (const float*)d_in[2];
  const float* Wv = (const float*)d_in[3];
  float* out = (float*)d_out;                // [output | Q | K | V], fp32
  float* Qo = out + 16777216;
  float* Ko = out + 2 * 16777216;
  float* Vo = out + 3 * 16777216;

  float* Sb = (float*)d_ws;
  const size_t S_E = 4194304;                // floats per batch of S
  const size_t ws_f = ws_size / 4;
  int nc = 1;
  if      (ws_f >= 8 * S_E) nc = 8;
  else if (ws_f >= 4 * S_E) nc = 4;
  else if (ws_f >= 2 * S_E) nc = 2;

  // QKV projections: C[16384,1024] = X[16384,1024] * W[1024,1024]
  mgemm<0><<<dim3(8, 128, 1), dim3(256), 0, stream>>>(
      X, Wq, Qo, 1024, 1024, 1024, 0LL, 0LL, 0LL, 1024, 0, 0, 1.0f);
  mgemm<0><<<dim3(8, 128, 1), dim3(256), 0, stream>>>(
      X, Wk, Ko, 1024, 1024, 1024, 0LL, 0LL, 0LL, 1024, 0, 0, 1.0f);
  mgemm<0><<<dim3(8, 128, 1), dim3(256), 0, stream>>>(
      X, Wv, Vo, 1024, 1024, 1024, 0LL, 0LL, 0LL, 1024, 0, 0, 1.0f);

  for (int z0 = 0; z0 < 8; z0 += nc) {
    // S = (1/32) Q K^T  (lower-triangle blocks only)
    mgemm<1><<<dim3(16, 16, nc), dim3(256), 0, stream>>>(
        Qo + (size_t)z0 * 2097152, Ko + (size_t)z0 * 2097152, Sb,
        1024, 1024, 2048, 2097152LL, 2097152LL, 4194304LL, 1024, 0, 1, 0.03125f);
    softmax_f32<<<dim3(2048, nc), dim3(256), 0, stream>>>(Sb);
    // O = P V  (k clipped at (q_tile+1)*128 by causality)
    mgemm<0><<<dim3(8, 16, nc), dim3(256), 0, stream>>>(
        Sb, Vo + (size_t)z0 * 2097152, out + (size_t)z0 * 2097152,
        2048, 1024, 1024, 4194304LL, 2097152LL, 2097152LL, 2048, 1, 0, 1.0f);
  }
}

// Round 3
// 1088.989 us; speedup vs baseline: 3.9495x; 1.3434x over previous
//
#include <hip/hip_runtime.h>

// ---------------------------------------------------------------------------
// Split-bf16 MFMA pipeline, v2: conversion hoisted OUT of the GEMMs.
//
// Pre-pass kernels split every fp32 operand once into bf16 (hi, lo) pairs
// (hi = truncated top 16 bits, lo = bf16 of exact remainder). All GEMMs are
// then a uniform C = A * B^T with bf16 k-contiguous operands, staged via
// global_load_lds width-16 (m97 structure): linear [128][32] LDS tiles whose
// 64-B rows are bank-conflict-free for the 16x16x32 fragment read pattern.
// 3-term MFMA (Ah*Bh + Ah*Bl + Al*Bh) keeps ~2^-16 relative product error.
//
// Projections fuse into ONE gemm vs W^T concat [Wq|Wk|Wv] (N=3072).
// Softmax writes P as packed bf16 hi|lo in place over the fp32 S buffer.
// ---------------------------------------------------------------------------

typedef __attribute__((ext_vector_type(8))) __bf16 bf16x8;
typedef __attribute__((ext_vector_type(4))) float f32x4;
typedef __attribute__((ext_vector_type(4))) unsigned short ushort4_t;
typedef __attribute__((ext_vector_type(8))) unsigned short ushort8_t;
typedef unsigned short u16;

__device__ __forceinline__ void split_bf16(float f, u16& hi, u16& lo) {
  const unsigned int b = __float_as_uint(f);
  const float r = f - __uint_as_float(b & 0xFFFF0000u);   // exact remainder
  hi = (u16)(b >> 16);
  lo = (u16)(__float_as_uint(r) >> 16);
}

// ---------------------------------------------------------------------------
// C[M,N] = A * B^T: A hi/lo [M][K], B hi/lo [N][K], both k-contiguous bf16.
// 128x128 tile, BK=32, 4 waves (2x2 of 64x64), global_load_lds staging.
// kclip: PV causal clip (kend = (by+1)*128). cskip: skip upper-tri blocks.
// nsplit: projection mode, C += (c0>>10)*16M (Q/K/V select), col = c0&1023.
// ---------------------------------------------------------------------------
__global__ __launch_bounds__(256)
void sgemm_bt(const u16* __restrict__ Agh, const u16* __restrict__ Agl,
              const u16* __restrict__ Bgh, const u16* __restrict__ Bgl,
              float* __restrict__ C,
              int lda, int ldb, int ldc, int K,
              long long bA, long long bB, long long bC,
              int kclip, int cskip, int nsplit, float scale) {
  if (cskip && (int)blockIdx.x > (int)blockIdx.y) return;
  const long long z = (long long)blockIdx.z;
  Agh += bA * z; Agl += bA * z;
  Bgh += bB * z; Bgl += bB * z;
  C   += bC * z;

  __shared__ u16 sm[16384];           // 32 KiB: Ah|Al|Bh|Bl, each [128][32]
  const int tid = threadIdx.x, lane = tid & 63, w = tid >> 6;
  const int r0 = (int)blockIdx.y << 7;
  const int c0 = (int)blockIdx.x << 7;
  int cC = c0;
  if (nsplit) { C += (size_t)(c0 >> 10) * 16777216; cC = c0 & 1023; }
  const int wr = (w >> 1) << 6, wc = (w & 1) << 6;
  const int l15 = lane & 15, l4 = lane >> 4;

  // staging role: wave w stages array w (Ah/Al/Bh/Bl), 8 x 1KiB per K-step
  const u16* sp = (w == 0) ? Agh : (w == 1) ? Agl : (w == 2) ? Bgh : Bgl;
  const int sld = (w < 2) ? lda : ldb;
  const int srb = (w < 2) ? r0 : c0;
  const u16* gp = sp + (size_t)(srb + (lane >> 2)) * sld + ((lane & 3) << 3);
  const size_t gstep = (size_t)sld << 4;          // 16 rows
  u16* lb = sm + (w << 12);

  f32x4 acc[4][4] = {};
  const int kend = kclip ? (((int)blockIdx.y + 1) << 7) : K;

  for (int k0 = 0; k0 < kend; k0 += 32, gp += 32) {
#pragma unroll
    for (int i = 0; i < 8; ++i)
      __builtin_amdgcn_global_load_lds(gp + (size_t)i * gstep, lb + (i << 9), 16, 0, 0);
    __syncthreads();

    bf16x8 bh[4], bl[4];
#pragma unroll
    for (int j = 0; j < 4; ++j) {
      const int off = (wc + (j << 4) + l15) * 32 + (l4 << 3);
      bh[j] = *(const bf16x8*)(sm + 8192 + off);
      bl[j] = *(const bf16x8*)(sm + 12288 + off);
    }
#pragma unroll
    for (int i = 0; i < 4; ++i) {
      const int off = (wr + (i << 4) + l15) * 32 + (l4 << 3);
      const bf16x8 ah = *(const bf16x8*)(sm + off);
      const bf16x8 al = *(const bf16x8*)(sm + 4096 + off);
#pragma unroll
      for (int j = 0; j < 4; ++j) {
        acc[i][j] = __builtin_amdgcn_mfma_f32_16x16x32_bf16(ah, bh[j], acc[i][j], 0, 0, 0);
        acc[i][j] = __builtin_amdgcn_mfma_f32_16x16x32_bf16(ah, bl[j], acc[i][j], 0, 0, 0);
        acc[i][j] = __builtin_amdgcn_mfma_f32_16x16x32_bf16(al, bh[j], acc[i][j], 0, 0, 0);
      }
    }
    __syncthreads();
  }

#pragma unroll
  for (int i = 0; i < 4; ++i) {
    const int rb = r0 + wr + (i << 4) + (l4 << 2);
#pragma unroll
    for (int j = 0; j < 4; ++j) {
      const int cc = cC + wc + (j << 4) + l15;
#pragma unroll
      for (int r = 0; r < 4; ++r)
        C[(size_t)(rb + r) * ldc + cc] = acc[i][j][r] * scale;
    }
  }
}

// linear split: fp32 -> bf16 hi + bf16 lo (grid = n/1024 blocks)
__global__ __launch_bounds__(256)
void split2(const float* __restrict__ src, u16* __restrict__ dh, u16* __restrict__ dl) {
  const size_t i = ((size_t)blockIdx.x * 256 + threadIdx.x) * 4;
  const float4 v = *(const float4*)(src + i);
  ushort4_t h, l;
  u16 h0, l0, h1, l1, h2, l2, h3, l3;
  split_bf16(v.x, h0, l0); split_bf16(v.y, h1, l1);
  split_bf16(v.z, h2, l2); split_bf16(v.w, h3, l3);
  h.x = h0; h.y = h1; h.z = h2; h.w = h3;
  l.x = l0; l.y = l1; l.z = l2; l.w = l3;
  *(ushort4_t*)(dh + i) = h;
  *(ushort4_t*)(dl + i) = l;
}

// transpose + split: src fp32 [R][ldS], dst hi/lo bf16 [(rowOff+)C][ldD] = src^T
// grid (C/64, R/64, batches), 64x64 tiles
__global__ __launch_bounds__(256)
void splitT(const float* __restrict__ src, u16* __restrict__ dh, u16* __restrict__ dl,
            int ldS, int ldD, long long bS, long long bD, int rowOff) {
  const long long z = (long long)blockIdx.z;
  src += bS * z; dh += bD * z; dl += bD * z;
  __shared__ float t[64][68];
  const int tid = threadIdx.x;
  const int c0 = (int)blockIdx.x << 6, r0 = (int)blockIdx.y << 6;
  const int rr = tid >> 4, cc4 = (tid & 15) << 2;
#pragma unroll
  for (int p = 0; p < 4; ++p) {
    const float4 v = *(const float4*)(src + (size_t)(r0 + (p << 4) + rr) * ldS + c0 + cc4);
    *(float4*)(&t[(p << 4) + rr][cc4]) = v;
  }
  __syncthreads();
#pragma unroll
  for (int p = 0; p < 4; ++p) {
    const int oc = (p << 4) + rr;                 // source col (= dst row) local
    ushort4_t h, l;
#pragma unroll
    for (int i = 0; i < 4; ++i) {
      u16 hh, ll; split_bf16(t[cc4 + i][oc], hh, ll);
      h[i] = hh; l[i] = ll;
    }
    const size_t o = (size_t)(rowOff + c0 + oc) * ldD + r0 + cc4;
    *(ushort4_t*)(dh + o) = h;
    *(ushort4_t*)(dl + o) = l;
  }
}

// causal softmax; reads fp32 row, writes P as packed bf16 hi|lo IN PLACE:
// row bytes [0,4096) = Ph (2048 bf16), [4096,8192) = Pl.
__global__ __launch_bounds__(256) void softmax_pack(float* __restrict__ S) {
  const int i = blockIdx.x;
  float* row = S + ((size_t)blockIdx.y * 2048 + (size_t)i) * 2048;
  const int tid = threadIdx.x;
  const int lane = tid & 63;
  const int wave = tid >> 6;
  const int j0 = tid * 8;

  float4 x0 = *(const float4*)(row + j0);
  float4 x1 = *(const float4*)(row + j0 + 4);
  float v[8] = {x0.x, x0.y, x0.z, x0.w, x1.x, x1.y, x1.z, x1.w};

  float m = -3.4e38f;
#pragma unroll
  for (int e = 0; e < 8; ++e)
    if (j0 + e <= i) m = fmaxf(m, v[e]);
  __shared__ float red[4];
#pragma unroll
  for (int off = 32; off; off >>= 1) m = fmaxf(m, __shfl_xor(m, off));
  if (lane == 0) red[wave] = m;
  __syncthreads();
  const float M = fmaxf(fmaxf(red[0], red[1]), fmaxf(red[2], red[3]));

  float p[8];
  float s = 0.f;
#pragma unroll
  for (int e = 0; e < 8; ++e) {
    p[e] = (j0 + e <= i) ? __expf(v[e] - M) : 0.f;
    s += p[e];
  }
#pragma unroll
  for (int off = 32; off; off >>= 1) s += __shfl_xor(s, off);
  __syncthreads();
  if (lane == 0) red[wave] = s;
  __syncthreads();
  const float inv = 1.0f / (red[0] + red[1] + red[2] + red[3]);

  ushort8_t hv, lv;
#pragma unroll
  for (int e = 0; e < 8; ++e) {
    u16 hh, ll; split_bf16(p[e] * inv, hh, ll);
    hv[e] = hh; lv[e] = ll;
  }
  u16* rp = (u16*)row;
  *(ushort8_t*)(rp + (size_t)tid * 8) = hv;
  *(ushort8_t*)(rp + 2048 + (size_t)tid * 8) = lv;
}

// ---------------------------------------------------------------------------
// Fallback path (small workspace): round-1 in-kernel-split mgemm, verbatim.
// ---------------------------------------------------------------------------
template<int BT>
__global__ __launch_bounds__(256)
void mgemm(const float* __restrict__ A, const float* __restrict__ B,
           float* __restrict__ C, int lda, int ldb, int ldc,
           long long bA, long long bB, long long bC,
           int K, int kmax_mode, int causal_skip, float scale) {
  if (causal_skip && (int)blockIdx.x > (int)blockIdx.y) return;
  A += bA * (long long)blockIdx.z;
  B += bB * (long long)blockIdx.z;
  C += bC * (long long)blockIdx.z;
  __shared__ u16 sm[4 * 128 * 40];
  u16* __restrict__ Ah = sm;
  u16* __restrict__ Al = sm + 5120;
  u16* __restrict__ Bh = sm + 10240;
  u16* __restrict__ Bl = sm + 15360;
  const int tid  = threadIdx.x;
  const int lane = tid & 63;
  const int wave = tid >> 6;
  const int wr = (wave >> 1) << 6;
  const int wc = (wave & 1) << 6;
  const int r0 = (int)blockIdx.y << 7;
  const int c0 = (int)blockIdx.x << 7;
  const int l15 = lane & 15, l4 = lane >> 4;
  const int sr = tid >> 3;
  const int sk = (tid & 7) << 2;
  f32x4 acc[4][4] = {};
  const int kend = kmax_mode ? (((int)blockIdx.y + 1) << 7) : K;
  for (int k0 = 0; k0 < kend; k0 += 32) {
#pragma unroll
    for (int p = 0; p < 4; ++p) {
      const int row = (p << 5) + sr;
      const float4 a = *(const float4*)(A + (size_t)(r0 + row) * lda + (k0 + sk));
      u16 h0, h1, h2, h3, l0, l1, l2, l3;
      split_bf16(a.x, h0, l0); split_bf16(a.y, h1, l1);
      split_bf16(a.z, h2, l2); split_bf16(a.w, h3, l3);
      *(ushort4_t*)(Ah + row * 40 + sk) = (ushort4_t){h0, h1, h2, h3};
      *(ushort4_t*)(Al + row * 40 + sk) = (ushort4_t){l0, l1, l2, l3};
    }
    if (BT) {
#pragma unroll
      for (int p = 0; p < 4; ++p) {
        const int row = (p << 5) + sr;
        const float4 b = *(const float4*)(B + (size_t)(c0 + row) * ldb + (k0 + sk));
        u16 h0, h1, h2, h3, l0, l1, l2, l3;
        split_bf16(b.x, h0, l0); split_bf16(b.y, h1, l1);
        split_bf16(b.z, h2, l2); split_bf16(b.w, h3, l3);
        *(ushort4_t*)(Bh + row * 40 + sk) = (ushort4_t){h0, h1, h2, h3};
        *(ushort4_t*)(Bl + row * 40 + sk) = (ushort4_t){l0, l1, l2, l3};
      }
    } else {
#pragma unroll
      for (int p = 0; p < 8; ++p) {
        const int e = (p << 8) + tid;
        const int k = e >> 6;
        const int n = (e & 63) << 1;
        const float2 b = *(const float2*)(B + (size_t)(k0 + k) * ldb + (c0 + n));
        u16 h0, l0, h1, l1;
        split_bf16(b.x, h0, l0); split_bf16(b.y, h1, l1);
        Bh[n * 40 + k] = h0; Bh[(n + 1) * 40 + k] = h1;
        Bl[n * 40 + k] = l0; Bl[(n + 1) * 40 + k] = l1;
      }
    }
    __syncthreads();
    bf16x8 bh[4], bl[4];
#pragma unroll
    for (int j = 0; j < 4; ++j) {
      const int n = wc + (j << 4) + l15;
      bh[j] = *(const bf16x8*)(Bh + n * 40 + (l4 << 3));
      bl[j] = *(const bf16x8*)(Bl + n * 40 + (l4 << 3));
    }
#pragma unroll
    for (int i = 0; i < 4; ++i) {
      const int m = wr + (i << 4) + l15;
      const bf16x8 ah = *(const bf16x8*)(Ah + m * 40 + (l4 << 3));
      const bf16x8 al = *(const bf16x8*)(Al + m * 40 + (l4 << 3));
#pragma unroll
      for (int j = 0; j < 4; ++j) {
        acc[i][j] = __builtin_amdgcn_mfma_f32_16x16x32_bf16(ah, bh[j], acc[i][j], 0, 0, 0);
        acc[i][j] = __builtin_amdgcn_mfma_f32_16x16x32_bf16(ah, bl[j], acc[i][j], 0, 0, 0);
        acc[i][j] = __builtin_amdgcn_mfma_f32_16x16x32_bf16(al, bh[j], acc[i][j], 0, 0, 0);
      }
    }
    __syncthreads();
  }
#pragma unroll
  for (int i = 0; i < 4; ++i) {
    const int rb = r0 + wr + (i << 4) + (l4 << 2);
#pragma unroll
    for (int j = 0; j < 4; ++j) {
      const int cc = c0 + wc + (j << 4) + l15;
#pragma unroll
      for (int r = 0; r < 4; ++r)
        C[(size_t)(rb + r) * ldc + cc] = acc[i][j][r] * scale;
    }
  }
}

__global__ __launch_bounds__(256) void softmax_f32(float* __restrict__ S) {
  const int i = blockIdx.x;
  float* row = S + ((size_t)blockIdx.y * 2048 + (size_t)i) * 2048;
  const int tid = threadIdx.x;
  const int lane = tid & 63;
  const int wave = tid >> 6;
  const int j0 = tid * 8;
  float4 x0 = *(const float4*)(row + j0);
  float4 x1 = *(const float4*)(row + j0 + 4);
  float v[8] = {x0.x, x0.y, x0.z, x0.w, x1.x, x1.y, x1.z, x1.w};
  float m = -3.4e38f;
#pragma unroll
  for (int e = 0; e < 8; ++e)
    if (j0 + e <= i) m = fmaxf(m, v[e]);
  __shared__ float red[4];
#pragma unroll
  for (int off = 32; off; off >>= 1) m = fmaxf(m, __shfl_xor(m, off));
  if (lane == 0) red[wave] = m;
  __syncthreads();
  const float M = fmaxf(fmaxf(red[0], red[1]), fmaxf(red[2], red[3]));
  float p[8];
  float s = 0.f;
#pragma unroll
  for (int e = 0; e < 8; ++e) {
    p[e] = (j0 + e <= i) ? __expf(v[e] - M) : 0.f;
    s += p[e];
  }
#pragma unroll
  for (int off = 32; off; off >>= 1) s += __shfl_xor(s, off);
  __syncthreads();
  if (lane == 0) red[wave] = s;
  __syncthreads();
  const float inv = 1.0f / (red[0] + red[1] + red[2] + red[3]);
  float4 o0 = {p[0] * inv, p[1] * inv, p[2] * inv, p[3] * inv};
  float4 o1 = {p[4] * inv, p[5] * inv, p[6] * inv, p[7] * inv};
  *(float4*)(row + j0) = o0;
  *(float4*)(row + j0 + 4) = o1;
}

extern "C" void kernel_launch(void* const* d_in, const int* in_sizes, int n_in,
                              void* d_out, int out_size, void* d_ws, size_t ws_size,
                              hipStream_t stream) {
  const float* X  = (const float*)d_in[0];
  const float* Wq = (const float*)d_in[1];
  const float* Wk = (const float*)d_in[2];
  const float* Wv = (const float*)d_in[3];
  float* out = (float*)d_out;                // [output | Q | K | V], fp32
  float* Qo = out + 16777216;
  float* Ko = out + 2 * 16777216;
  float* Vo = out + 3 * 16777216;
  char* wsb = (char*)d_ws;

  const unsigned long long PER_BATCH = 41943040ull;  // S(16Mi)+QK splits(16Mi)+VT(8Mi)

  if (ws_size >= PER_BATCH) {
    // ---------------- fast path: pre-split operands ----------------
    // projection phase layout: Xh | Xl | WTh | WTl
    int xc = 1;
    while (xc < 8 && (67108864ull / xc + 12582912ull) > ws_size) xc <<= 1;
    const int Mx = 16384 / xc;
    u16* Xh  = (u16*)wsb;
    u16* Xl  = Xh + (size_t)Mx * 1024;
    u16* WTh = Xl + (size_t)Mx * 1024;
    u16* WTl = WTh + 3145728;

    splitT<<<dim3(16, 16, 1), 256, 0, stream>>>(Wq, WTh, WTl, 1024, 1024, 0, 0, 0);
    splitT<<<dim3(16, 16, 1), 256, 0, stream>>>(Wk, WTh, WTl, 1024, 1024, 0, 0, 1024);
    splitT<<<dim3(16, 16, 1), 256, 0, stream>>>(Wv, WTh, WTl, 1024, 1024, 0, 0, 2048);

    for (int mc = 0; mc < xc; ++mc) {
      const float* Xc = X + (size_t)mc * Mx * 1024;
      split2<<<dim3(Mx), 256, 0, stream>>>(Xc, Xh, Xl);
      // fused QKV: C = X * [Wq|Wk|Wv]^T, N=3072, nsplit routes to Q/K/V
      sgemm_bt<<<dim3(24, Mx / 128, 1), 256, 0, stream>>>(
          Xh, Xl, WTh, WTl, out + 16777216 + (size_t)mc * Mx * 1024,
          1024, 1024, 1024, 1024, 0LL, 0LL, 0LL, 0, 0, 1, 1.0f);
    }

    // attention phase layout: S(fp32,nc) | Qh Ql Kh Kl (nc ea) | VTh VTl
    int nc = (int)(ws_size / PER_BATCH);
    if (nc > 8) nc = 8;
    float* Sb = (float*)wsb;
    u16* Qh = (u16*)(wsb + (size_t)nc * 16777216);
    const size_t R = (size_t)nc * 2097152;
    u16* Ql = Qh + R; u16* Kh = Qh + 2 * R; u16* Kl = Qh + 3 * R;
    u16* VTh = Qh + 4 * R; u16* VTl = Qh + 5 * R;

    for (int z0 = 0; z0 < 8; z0 += nc) {
      const int n = (8 - z0 < nc) ? (8 - z0) : nc;
      split2<<<dim3(n * 2048), 256, 0, stream>>>(Qo + (size_t)z0 * 2097152, Qh, Ql);
      split2<<<dim3(n * 2048), 256, 0, stream>>>(Ko + (size_t)z0 * 2097152, Kh, Kl);
      splitT<<<dim3(16, 32, n), 256, 0, stream>>>(Vo + (size_t)z0 * 2097152, VTh, VTl,
                                                  1024, 2048, 2097152LL, 2097152LL, 0);
      // S = (1/32) Q K^T, lower-triangle blocks
      sgemm_bt<<<dim3(16, 16, n), 256, 0, stream>>>(
          Qh, Ql, Kh, Kl, Sb, 1024, 1024, 2048, 1024,
          2097152LL, 2097152LL, 4194304LL, 0, 1, 0, 0.03125f);
      softmax_pack<<<dim3(2048, n), 256, 0, stream>>>(Sb);
      // O = P V: A = packed P (hi at row+0, lo at row+2048 shorts), B = V^T
      sgemm_bt<<<dim3(8, 16, n), 256, 0, stream>>>(
          (const u16*)Sb, (const u16*)Sb + 2048, VTh, VTl,
          out + (size_t)z0 * 2097152, 4096, 2048, 1024, 2048,
          8388608LL, 2097152LL, 2097152LL, 1, 0, 0, 1.0f);
    }
  } else {
    // ---------------- fallback: round-1 path (small ws) ----------------
    float* Sb = (float*)d_ws;
    const size_t S_E = 4194304;
    const size_t ws_f = ws_size / 4;
    int nc = 1;
    if      (ws_f >= 8 * S_E) nc = 8;
    else if (ws_f >= 4 * S_E) nc = 4;
    else if (ws_f >= 2 * S_E) nc = 2;
    mgemm<0><<<dim3(8, 128, 1), dim3(256), 0, stream>>>(
        X, Wq, Qo, 1024, 1024, 1024, 0LL, 0LL, 0LL, 1024, 0, 0, 1.0f);
    mgemm<0><<<dim3(8, 128, 1), dim3(256), 0, stream>>>(
        X, Wk, Ko, 1024, 1024, 1024, 0LL, 0LL, 0LL, 1024, 0, 0, 1.0f);
    mgemm<0><<<dim3(8, 128, 1), dim3(256), 0, stream>>>(
        X, Wv, Vo, 1024, 1024, 1024, 0LL, 0LL, 0LL, 1024, 0, 0, 1.0f);
    for (int z0 = 0; z0 < 8; z0 += nc) {
      mgemm<1><<<dim3(16, 16, nc), dim3(256), 0, stream>>>(
          Qo + (size_t)z0 * 2097152, Ko + (size_t)z0 * 2097152, Sb,
          1024, 1024, 2048, 2097152LL, 2097152LL, 4194304LL, 1024, 0, 1, 0.03125f);
      softmax_f32<<<dim3(2048, nc), dim3(256), 0, stream>>>(Sb);
      mgemm<0><<<dim3(8, 16, nc), dim3(256), 0, stream>>>(
          Sb, Vo + (size_t)z0 * 2097152, out + (size_t)z0 * 2097152,
          2048, 1024, 1024, 4194304LL, 2097152LL, 2097152LL, 2048, 1, 0, 1.0f);
    }
  }
}

// Round 4
// 1054.375 us; speedup vs baseline: 4.0791x; 1.0328x over previous
//
#include <hip/hip_runtime.h>

// ---------------------------------------------------------------------------
// Split-bf16 MFMA pipeline, v3: LDS-BW-roofline fix via 8x4 register blocking.
//
// v2 measured MfmaUtil 48.5% == the predicted LDS-read roofline for a 64x64
// wave tile (4x4 frags): (4+4) frags x 2(hi/lo) KB per 48 MFMA -> 273 B/cyc
// demand vs 128 B/cyc LDS peak. v3 moves to wave tile 128x64 (8x4 frags):
// (8+4)x2 KB per 96 MFMA -> 205 B/cyc -> ceiling 62.5%.
//
// Block 256x128, 4 waves (2M x 2N of 128x64), BK=32, global_load_lds staging
// (wave roles: w0=Ah x16, w1=Al x16, w2=Bh x8, w3=Bl x8 1-KB issues).
// 3-term MFMA (Ah*Bh + Ah*Bl + Al*Bh) numerics identical to v2.
// ---------------------------------------------------------------------------

typedef __attribute__((ext_vector_type(8))) __bf16 bf16x8;
typedef __attribute__((ext_vector_type(4))) float f32x4;
typedef __attribute__((ext_vector_type(4))) unsigned short ushort4_t;
typedef __attribute__((ext_vector_type(8))) unsigned short ushort8_t;
typedef unsigned short u16;

__device__ __forceinline__ void split_bf16(float f, u16& hi, u16& lo) {
  const unsigned int b = __float_as_uint(f);
  const float r = f - __uint_as_float(b & 0xFFFF0000u);   // exact remainder
  hi = (u16)(b >> 16);
  lo = (u16)(__float_as_uint(r) >> 16);
}

// ---------------------------------------------------------------------------
// C[M,N] = A * B^T: A hi/lo [M][K], B hi/lo [N][K], both k-contiguous bf16.
// Tile 256x128, BK=32. kclip: PV causal clip (kend=(by+1)*256).
// cskip: skip blocks fully above the diagonal (bx > 2*by+1).
// nsplit: projection mode, C += (c0>>10)*16M (Q/K/V select), col = c0&1023.
// ---------------------------------------------------------------------------
__global__ __launch_bounds__(256, 2)
void sgemm_bt(const u16* __restrict__ Agh, const u16* __restrict__ Agl,
              const u16* __restrict__ Bgh, const u16* __restrict__ Bgl,
              float* __restrict__ C,
              int lda, int ldb, int ldc, int K,
              long long bA, long long bB, long long bC,
              int kclip, int cskip, int nsplit, float scale) {
  const int bx = (int)blockIdx.x, by = (int)blockIdx.y;
  if (cskip && bx > 2 * by + 1) return;
  const long long z = (long long)blockIdx.z;
  Agh += bA * z; Agl += bA * z;
  Bgh += bB * z; Bgl += bB * z;
  C   += bC * z;

  // 48 KiB: Ah [256][32] | Al [256][32] | Bh [128][32] | Bl [128][32]
  __shared__ u16 sm[24576];
  const int tid = threadIdx.x, lane = tid & 63, w = tid >> 6;
  const int r0 = by << 8;
  const int c0 = bx << 7;
  int cC = c0;
  if (nsplit) { C += (size_t)(c0 >> 10) * 16777216; cC = c0 & 1023; }
  const int wr = (w >> 1) << 7;              // wave M offset: 0 / 128
  const int wc = (w & 1) << 6;               // wave N offset: 0 / 64
  const int l15 = lane & 15, l4 = lane >> 4;

  // staging roles: w0 -> Ah (16 KiB), w1 -> Al, w2 -> Bh (8 KiB), w3 -> Bl
  const u16* sp = (w == 0) ? Agh : (w == 1) ? Agl : (w == 2) ? Bgh : Bgl;
  const int sld = (w < 2) ? lda : ldb;
  const int srb = (w < 2) ? r0 : c0;
  const u16* gp = sp + (size_t)(srb + (lane >> 2)) * sld + ((lane & 3) << 3);
  const size_t gstep = (size_t)sld << 4;     // 16 rows per 1-KiB issue
  u16* lb = sm + ((w == 0) ? 0 : (w == 1) ? 8192 : (w == 2) ? 16384 : 20480);

  f32x4 acc[8][4] = {};
  const int kend = kclip ? ((by + 1) << 8) : K;

  for (int k0 = 0; k0 < kend; k0 += 32, gp += 32) {
    if (w < 2) {
#pragma unroll
      for (int i = 0; i < 16; ++i)
        __builtin_amdgcn_global_load_lds(gp + (size_t)i * gstep, lb + (i << 9), 16, 0, 0);
    } else {
#pragma unroll
      for (int i = 0; i < 8; ++i)
        __builtin_amdgcn_global_load_lds(gp + (size_t)i * gstep, lb + (i << 9), 16, 0, 0);
    }
    __syncthreads();

    bf16x8 bh[4], bl[4];
#pragma unroll
    for (int j = 0; j < 4; ++j) {
      const int off = (wc + (j << 4) + l15) * 32 + (l4 << 3);
      bh[j] = *(const bf16x8*)(sm + 16384 + off);
      bl[j] = *(const bf16x8*)(sm + 20480 + off);
    }
#pragma unroll
    for (int i = 0; i < 8; ++i) {
      const int off = (wr + (i << 4) + l15) * 32 + (l4 << 3);
      const bf16x8 ah = *(const bf16x8*)(sm + off);
      const bf16x8 al = *(const bf16x8*)(sm + 8192 + off);
#pragma unroll
      for (int j = 0; j < 4; ++j) {
        acc[i][j] = __builtin_amdgcn_mfma_f32_16x16x32_bf16(ah, bh[j], acc[i][j], 0, 0, 0);
        acc[i][j] = __builtin_amdgcn_mfma_f32_16x16x32_bf16(ah, bl[j], acc[i][j], 0, 0, 0);
        acc[i][j] = __builtin_amdgcn_mfma_f32_16x16x32_bf16(al, bh[j], acc[i][j], 0, 0, 0);
      }
    }
    __syncthreads();
  }

#pragma unroll
  for (int i = 0; i < 8; ++i) {
    const int rb = r0 + wr + (i << 4) + (l4 << 2);
#pragma unroll
    for (int j = 0; j < 4; ++j) {
      const int cc = cC + wc + (j << 4) + l15;
#pragma unroll
      for (int r = 0; r < 4; ++r)
        C[(size_t)(rb + r) * ldc + cc] = acc[i][j][r] * scale;
    }
  }
}

// linear split: fp32 -> bf16 hi + bf16 lo (grid = n/1024 blocks)
__global__ __launch_bounds__(256)
void split2(const float* __restrict__ src, u16* __restrict__ dh, u16* __restrict__ dl) {
  const size_t i = ((size_t)blockIdx.x * 256 + threadIdx.x) * 4;
  const float4 v = *(const float4*)(src + i);
  ushort4_t h, l;
  u16 h0, l0, h1, l1, h2, l2, h3, l3;
  split_bf16(v.x, h0, l0); split_bf16(v.y, h1, l1);
  split_bf16(v.z, h2, l2); split_bf16(v.w, h3, l3);
  h.x = h0; h.y = h1; h.z = h2; h.w = h3;
  l.x = l0; l.y = l1; l.z = l2; l.w = l3;
  *(ushort4_t*)(dh + i) = h;
  *(ushort4_t*)(dl + i) = l;
}

// transpose + split: src fp32 [R][ldS], dst hi/lo bf16 [(rowOff+)C][ldD] = src^T
// grid (C/64, R/64, batches), 64x64 tiles
__global__ __launch_bounds__(256)
void splitT(const float* __restrict__ src, u16* __restrict__ dh, u16* __restrict__ dl,
            int ldS, int ldD, long long bS, long long bD, int rowOff) {
  const long long z = (long long)blockIdx.z;
  src += bS * z; dh += bD * z; dl += bD * z;
  __shared__ float t[64][68];
  const int tid = threadIdx.x;
  const int c0 = (int)blockIdx.x << 6, r0 = (int)blockIdx.y << 6;
  const int rr = tid >> 4, cc4 = (tid & 15) << 2;
#pragma unroll
  for (int p = 0; p < 4; ++p) {
    const float4 v = *(const float4*)(src + (size_t)(r0 + (p << 4) + rr) * ldS + c0 + cc4);
    *(float4*)(&t[(p << 4) + rr][cc4]) = v;
  }
  __syncthreads();
#pragma unroll
  for (int p = 0; p < 4; ++p) {
    const int oc = (p << 4) + rr;                 // source col (= dst row) local
    ushort4_t h, l;
#pragma unroll
    for (int i = 0; i < 4; ++i) {
      u16 hh, ll; split_bf16(t[cc4 + i][oc], hh, ll);
      h[i] = hh; l[i] = ll;
    }
    const size_t o = (size_t)(rowOff + c0 + oc) * ldD + r0 + cc4;
    *(ushort4_t*)(dh + o) = h;
    *(ushort4_t*)(dl + o) = l;
  }
}

// causal softmax; reads fp32 row, writes P as packed bf16 hi|lo IN PLACE:
// row bytes [0,4096) = Ph (2048 bf16), [4096,8192) = Pl.
__global__ __launch_bounds__(256) void softmax_pack(float* __restrict__ S) {
  const int i = blockIdx.x;
  float* row = S + ((size_t)blockIdx.y * 2048 + (size_t)i) * 2048;
  const int tid = threadIdx.x;
  const int lane = tid & 63;
  const int wave = tid >> 6;
  const int j0 = tid * 8;

  float4 x0 = *(const float4*)(row + j0);
  float4 x1 = *(const float4*)(row + j0 + 4);
  float v[8] = {x0.x, x0.y, x0.z, x0.w, x1.x, x1.y, x1.z, x1.w};

  float m = -3.4e38f;
#pragma unroll
  for (int e = 0; e < 8; ++e)
    if (j0 + e <= i) m = fmaxf(m, v[e]);
  __shared__ float red[4];
#pragma unroll
  for (int off = 32; off; off >>= 1) m = fmaxf(m, __shfl_xor(m, off));
  if (lane == 0) red[wave] = m;
  __syncthreads();
  const float M = fmaxf(fmaxf(red[0], red[1]), fmaxf(red[2], red[3]));

  float p[8];
  float s = 0.f;
#pragma unroll
  for (int e = 0; e < 8; ++e) {
    p[e] = (j0 + e <= i) ? __expf(v[e] - M) : 0.f;
    s += p[e];
  }
#pragma unroll
  for (int off = 32; off; off >>= 1) s += __shfl_xor(s, off);
  __syncthreads();
  if (lane == 0) red[wave] = s;
  __syncthreads();
  const float inv = 1.0f / (red[0] + red[1] + red[2] + red[3]);

  ushort8_t hv, lv;
#pragma unroll
  for (int e = 0; e < 8; ++e) {
    u16 hh, ll; split_bf16(p[e] * inv, hh, ll);
    hv[e] = hh; lv[e] = ll;
  }
  u16* rp = (u16*)row;
  *(ushort8_t*)(rp + (size_t)tid * 8) = hv;
  *(ushort8_t*)(rp + 2048 + (size_t)tid * 8) = lv;
}

// ---------------------------------------------------------------------------
// Fallback path (small workspace): round-1 in-kernel-split mgemm, verbatim.
// ---------------------------------------------------------------------------
template<int BT>
__global__ __launch_bounds__(256)
void mgemm(const float* __restrict__ A, const float* __restrict__ B,
           float* __restrict__ C, int lda, int ldb, int ldc,
           long long bA, long long bB, long long bC,
           int K, int kmax_mode, int causal_skip, float scale) {
  if (causal_skip && (int)blockIdx.x > (int)blockIdx.y) return;
  A += bA * (long long)blockIdx.z;
  B += bB * (long long)blockIdx.z;
  C += bC * (long long)blockIdx.z;
  __shared__ u16 sm[4 * 128 * 40];
  u16* __restrict__ Ah = sm;
  u16* __restrict__ Al = sm + 5120;
  u16* __restrict__ Bh = sm + 10240;
  u16* __restrict__ Bl = sm + 15360;
  const int tid  = threadIdx.x;
  const int lane = tid & 63;
  const int wave = tid >> 6;
  const int wr = (wave >> 1) << 6;
  const int wc = (wave & 1) << 6;
  const int r0 = (int)blockIdx.y << 7;
  const int c0 = (int)blockIdx.x << 7;
  const int l15 = lane & 15, l4 = lane >> 4;
  const int sr = tid >> 3;
  const int sk = (tid & 7) << 2;
  f32x4 acc[4][4] = {};
  const int kend = kmax_mode ? (((int)blockIdx.y + 1) << 7) : K;
  for (int k0 = 0; k0 < kend; k0 += 32) {
#pragma unroll
    for (int p = 0; p < 4; ++p) {
      const int row = (p << 5) + sr;
      const float4 a = *(const float4*)(A + (size_t)(r0 + row) * lda + (k0 + sk));
      u16 h0, h1, h2, h3, l0, l1, l2, l3;
      split_bf16(a.x, h0, l0); split_bf16(a.y, h1, l1);
      split_bf16(a.z, h2, l2); split_bf16(a.w, h3, l3);
      *(ushort4_t*)(Ah + row * 40 + sk) = (ushort4_t){h0, h1, h2, h3};
      *(ushort4_t*)(Al + row * 40 + sk) = (ushort4_t){l0, l1, l2, l3};
    }
    if (BT) {
#pragma unroll
      for (int p = 0; p < 4; ++p) {
        const int row = (p << 5) + sr;
        const float4 b = *(const float4*)(B + (size_t)(c0 + row) * ldb + (k0 + sk));
        u16 h0, h1, h2, h3, l0, l1, l2, l3;
        split_bf16(b.x, h0, l0); split_bf16(b.y, h1, l1);
        split_bf16(b.z, h2, l2); split_bf16(b.w, h3, l3);
        *(ushort4_t*)(Bh + row * 40 + sk) = (ushort4_t){h0, h1, h2, h3};
        *(ushort4_t*)(Bl + row * 40 + sk) = (ushort4_t){l0, l1, l2, l3};
      }
    } else {
#pragma unroll
      for (int p = 0; p < 8; ++p) {
        const int e = (p << 8) + tid;
        const int k = e >> 6;
        const int n = (e & 63) << 1;
        const float2 b = *(const float2*)(B + (size_t)(k0 + k) * ldb + (c0 + n));
        u16 h0, l0, h1, l1;
        split_bf16(b.x, h0, l0); split_bf16(b.y, h1, l1);
        Bh[n * 40 + k] = h0; Bh[(n + 1) * 40 + k] = h1;
        Bl[n * 40 + k] = l0; Bl[(n + 1) * 40 + k] = l1;
      }
    }
    __syncthreads();
    bf16x8 bh[4], bl[4];
#pragma unroll
    for (int j = 0; j < 4; ++j) {
      const int n = wc + (j << 4) + l15;
      bh[j] = *(const bf16x8*)(Bh + n * 40 + (l4 << 3));
      bl[j] = *(const bf16x8*)(Bl + n * 40 + (l4 << 3));
    }
#pragma unroll
    for (int i = 0; i < 4; ++i) {
      const int m = wr + (i << 4) + l15;
      const bf16x8 ah = *(const bf16x8*)(Ah + m * 40 + (l4 << 3));
      const bf16x8 al = *(const bf16x8*)(Al + m * 40 + (l4 << 3));
#pragma unroll
      for (int j = 0; j < 4; ++j) {
        acc[i][j] = __builtin_amdgcn_mfma_f32_16x16x32_bf16(ah, bh[j], acc[i][j], 0, 0, 0);
        acc[i][j] = __builtin_amdgcn_mfma_f32_16x16x32_bf16(ah, bl[j], acc[i][j], 0, 0, 0);
        acc[i][j] = __builtin_amdgcn_mfma_f32_16x16x32_bf16(al, bh[j], acc[i][j], 0, 0, 0);
      }
    }
    __syncthreads();
  }
#pragma unroll
  for (int i = 0; i < 4; ++i) {
    const int rb = r0 + wr + (i << 4) + (l4 << 2);
#pragma unroll
    for (int j = 0; j < 4; ++j) {
      const int cc = c0 + wc + (j << 4) + l15;
#pragma unroll
      for (int r = 0; r < 4; ++r)
        C[(size_t)(rb + r) * ldc + cc] = acc[i][j][r] * scale;
    }
  }
}

__global__ __launch_bounds__(256) void softmax_f32(float* __restrict__ S) {
  const int i = blockIdx.x;
  float* row = S + ((size_t)blockIdx.y * 2048 + (size_t)i) * 2048;
  const int tid = threadIdx.x;
  const int lane = tid & 63;
  const int wave = tid >> 6;
  const int j0 = tid * 8;
  float4 x0 = *(const float4*)(row + j0);
  float4 x1 = *(const float4*)(row + j0 + 4);
  float v[8] = {x0.x, x0.y, x0.z, x0.w, x1.x, x1.y, x1.z, x1.w};
  float m = -3.4e38f;
#pragma unroll
  for (int e = 0; e < 8; ++e)
    if (j0 + e <= i) m = fmaxf(m, v[e]);
  __shared__ float red[4];
#pragma unroll
  for (int off = 32; off; off >>= 1) m = fmaxf(m, __shfl_xor(m, off));
  if (lane == 0) red[wave] = m;
  __syncthreads();
  const float M = fmaxf(fmaxf(red[0], red[1]), fmaxf(red[2], red[3]));
  float p[8];
  float s = 0.f;
#pragma unroll
  for (int e = 0; e < 8; ++e) {
    p[e] = (j0 + e <= i) ? __expf(v[e] - M) : 0.f;
    s += p[e];
  }
#pragma unroll
  for (int off = 32; off; off >>= 1) s += __shfl_xor(s, off);
  __syncthreads();
  if (lane == 0) red[wave] = s;
  __syncthreads();
  const float inv = 1.0f / (red[0] + red[1] + red[2] + red[3]);
  float4 o0 = {p[0] * inv, p[1] * inv, p[2] * inv, p[3] * inv};
  float4 o1 = {p[4] * inv, p[5] * inv, p[6] * inv, p[7] * inv};
  *(float4*)(row + j0) = o0;
  *(float4*)(row + j0 + 4) = o1;
}

extern "C" void kernel_launch(void* const* d_in, const int* in_sizes, int n_in,
                              void* d_out, int out_size, void* d_ws, size_t ws_size,
                              hipStream_t stream) {
  const float* X  = (const float*)d_in[0];
  const float* Wq = (const float*)d_in[1];
  const float* Wk = (const float*)d_in[2];
  const float* Wv = (const float*)d_in[3];
  float* out = (float*)d_out;                // [output | Q | K | V], fp32
  float* Qo = out + 16777216;
  float* Ko = out + 2 * 16777216;
  float* Vo = out + 3 * 16777216;
  char* wsb = (char*)d_ws;

  const unsigned long long PER_BATCH = 41943040ull;  // S(16Mi)+QK splits(16Mi)+VT(8Mi)

  if (ws_size >= PER_BATCH) {
    // ---------------- fast path: pre-split operands ----------------
    // projection phase layout: Xh | Xl | WTh | WTl
    int xc = 1;
    while (xc < 8 && (67108864ull / xc + 12582912ull) > ws_size) xc <<= 1;
    const int Mx = 16384 / xc;
    u16* Xh  = (u16*)wsb;
    u16* Xl  = Xh + (size_t)Mx * 1024;
    u16* WTh = Xl + (size_t)Mx * 1024;
    u16* WTl = WTh + 3145728;

    splitT<<<dim3(16, 16, 1), 256, 0, stream>>>(Wq, WTh, WTl, 1024, 1024, 0, 0, 0);
    splitT<<<dim3(16, 16, 1), 256, 0, stream>>>(Wk, WTh, WTl, 1024, 1024, 0, 0, 1024);
    splitT<<<dim3(16, 16, 1), 256, 0, stream>>>(Wv, WTh, WTl, 1024, 1024, 0, 0, 2048);

    for (int mc = 0; mc < xc; ++mc) {
      const float* Xc = X + (size_t)mc * Mx * 1024;
      split2<<<dim3(Mx), 256, 0, stream>>>(Xc, Xh, Xl);
      // fused QKV: C = X * [Wq|Wk|Wv]^T, N=3072, nsplit routes to Q/K/V
      sgemm_bt<<<dim3(24, Mx / 256, 1), 256, 0, stream>>>(
          Xh, Xl, WTh, WTl, out + 16777216 + (size_t)mc * Mx * 1024,
          1024, 1024, 1024, 1024, 0LL, 0LL, 0LL, 0, 0, 1, 1.0f);
    }

    // attention phase layout: S(fp32,nc) | Qh Ql Kh Kl (nc ea) | VTh VTl
    int nc = (int)(ws_size / PER_BATCH);
    if (nc > 8) nc = 8;
    float* Sb = (float*)wsb;
    u16* Qh = (u16*)(wsb + (size_t)nc * 16777216);
    const size_t R = (size_t)nc * 2097152;
    u16* Ql = Qh + R; u16* Kh = Qh + 2 * R; u16* Kl = Qh + 3 * R;
    u16* VTh = Qh + 4 * R; u16* VTl = Qh + 5 * R;

    for (int z0 = 0; z0 < 8; z0 += nc) {
      const int n = (8 - z0 < nc) ? (8 - z0) : nc;
      split2<<<dim3(n * 2048), 256, 0, stream>>>(Qo + (size_t)z0 * 2097152, Qh, Ql);
      split2<<<dim3(n * 2048), 256, 0, stream>>>(Ko + (size_t)z0 * 2097152, Kh, Kl);
      splitT<<<dim3(16, 32, n), 256, 0, stream>>>(Vo + (size_t)z0 * 2097152, VTh, VTl,
                                                  1024, 2048, 2097152LL, 2097152LL, 0);
      // S = (1/32) Q K^T, blocks fully above diagonal skipped
      sgemm_bt<<<dim3(16, 8, n), 256, 0, stream>>>(
          Qh, Ql, Kh, Kl, Sb, 1024, 1024, 2048, 1024,
          2097152LL, 2097152LL, 4194304LL, 0, 1, 0, 0.03125f);
      softmax_pack<<<dim3(2048, n), 256, 0, stream>>>(Sb);
      // O = P V: A = packed P (hi at row+0, lo at row+2048 shorts), B = V^T
      sgemm_bt<<<dim3(8, 8, n), 256, 0, stream>>>(
          (const u16*)Sb, (const u16*)Sb + 2048, VTh, VTl,
          out + (size_t)z0 * 2097152, 4096, 2048, 1024, 2048,
          8388608LL, 2097152LL, 2097152LL, 1, 0, 0, 1.0f);
    }
  } else {
    // ---------------- fallback: round-1 path (small ws) ----------------
    float* Sb = (float*)d_ws;
    const size_t S_E = 4194304;
    const size_t ws_f = ws_size / 4;
    int nc = 1;
    if      (ws_f >= 8 * S_E) nc = 8;
    else if (ws_f >= 4 * S_E) nc = 4;
    else if (ws_f >= 2 * S_E) nc = 2;
    mgemm<0><<<dim3(8, 128, 1), dim3(256), 0, stream>>>(
        X, Wq, Qo, 1024, 1024, 1024, 0LL, 0LL, 0LL, 1024, 0, 0, 1.0f);
    mgemm<0><<<dim3(8, 128, 1), dim3(256), 0, stream>>>(
        X, Wk, Ko, 1024, 1024, 1024, 0LL, 0LL, 0LL, 1024, 0, 0, 1.0f);
    mgemm<0><<<dim3(8, 128, 1), dim3(256), 0, stream>>>(
        X, Wv, Vo, 1024, 1024, 1024, 0LL, 0LL, 0LL, 1024, 0, 0, 1.0f);
    for (int z0 = 0; z0 < 8; z0 += nc) {
      mgemm<1><<<dim3(16, 16, nc), dim3(256), 0, stream>>>(
          Qo + (size_t)z0 * 2097152, Ko + (size_t)z0 * 2097152, Sb,
          1024, 1024, 2048, 2097152LL, 2097152LL, 4194304LL, 1024, 0, 1, 0.03125f);
      softmax_f32<<<dim3(2048, nc), dim3(256), 0, stream>>>(Sb);
      mgemm<0><<<dim3(8, 16, nc), dim3(256), 0, stream>>>(
          Sb, Vo + (size_t)z0 * 2097152, out + (size_t)z0 * 2097152,
          2048, 1024, 1024, 4194304LL, 2097152LL, 2097152LL, 2048, 1, 0, 1.0f);
    }
  }
}